// Round 5
// baseline (30713.773 us; speedup 1.0000x reference)
//
#include <hip/hip_runtime.h>
#include <stdint.h>

#define TSTEPS 8192
#define HDIM 512

typedef unsigned long long ull;

// ---------------------------------------------------------------------------
__device__ __forceinline__ ull pack_th(unsigned tag, float v) {
    union { float f; unsigned u; } x; x.f = v;
    return ((ull)tag << 32) | (ull)x.u;
}
__device__ __forceinline__ float unpack_v(ull p) {
    union { unsigned u; float f; } x; x.u = (unsigned)p;
    return x.f;
}

// ---------------------------------------------------------------------------
// Fused 2-layer persistent LSTM, register-distributed, wave-autonomous.
// 256 WGs x 256 threads = 1 WG/CU; wave = one hidden unit j.
//   blocks   0..127: layer 1 (j = bid*4+wave).   feed = x(t) (global loads)
//   blocks 128..255: layer 2.                    feed = h1(t) (ring0 poll)
// Lane l holds W[r][l+64u] for r=0..3 (gate rows of j), u=0..7:
//   32 weights/matrix, 64 total -> far below spill pressure (the R3 killer).
// h never touches LDS: lanes poll {tag,value} 8B slots straight into
// registers; 6-level shfl_xor butterfly x4 accumulators gives every lane all
// 4 gate sums. No __shared__, no __syncthreads.
//
// SENTINEL PRE-SPIN (new): spinning waves load ONE slot (all 64 lanes same
// address -> 1 transaction/round) instead of all 512 (4KB/wave/round), then
// bulk-load once + per-slot tag-verify fixup (each slot is self-validating,
// so no ordering assumptions). Kills the fabric flood that would otherwise
// inflate detect latency.
//
// ring0/ring1 are FULL-HISTORY (slot s = state after s steps, tag s+1;
// written once -> L1 never waits for L2, no back-pressure).
// Tags <= 8194: poison 0xAAAAAAAA / 0x00000000 never match.
// ---------------------------------------------------------------------------
__global__ __launch_bounds__(256, 1) void lstm_fused(
    const float* __restrict__ x,      // [T][512]
    const float* __restrict__ Whh0,   // [2048][512]
    const float* __restrict__ Wih0,   // [2048][512]
    const float* __restrict__ bih0,   // [2048]
    const float* __restrict__ bhh0,   // [2048]
    const float* __restrict__ Wih1,   // [2048][512]
    const float* __restrict__ Whh1,   // [2048][512]
    const float* __restrict__ bih1,   // [2048]
    const float* __restrict__ bhh1,   // [2048]
    const float* __restrict__ h0,     // [2][512]
    const float* __restrict__ c0,     // [2][512]
    float* __restrict__ h2seq,        // [T][512]
    ull* __restrict__ ring0,          // [T+2][512]
    ull* __restrict__ ring1)          // [T+2][512]
{
    const int L2   = (blockIdx.x >= 128) ? 1 : 0;
    const int wb   = L2 ? (int)blockIdx.x - 128 : (int)blockIdx.x;
    const int tid  = threadIdx.x;
    const int wave = tid >> 6;
    const int lane = tid & 63;
    const int j    = wb * 4 + wave;
    const int SENT = (j + 257) & 511;   // per-wave sentinel slot

    // ---- register-resident weights: wA = recurrent, wB = feed -------------
    float wA[4][8], wB[4][8];
    {
        const float* WA = L2 ? Whh1 : Whh0;
        const float* WB = L2 ? Wih1 : Wih0;
#pragma unroll
        for (int r = 0; r < 4; ++r) {
            const size_t rb = (size_t)(r * HDIM + j) * HDIM + lane;
#pragma unroll
            for (int u = 0; u < 8; ++u) {
                wA[r][u] = WA[rb + 64 * u];
                wB[r][u] = WB[rb + 64 * u];
            }
        }
    }
    float bb[4];
#pragma unroll
    for (int r = 0; r < 4; ++r)
        bb[r] = L2 ? (bih1[r * HDIM + j] + bhh1[r * HDIM + j])
                   : (bih0[r * HDIM + j] + bhh0[r * HDIM + j]);
    float c = c0[(L2 ? HDIM : 0) + j];

    ull* rring = L2 ? ring1 : ring0;   // recurrent (self) ring

    // initial state -> slot 0, tag 1 (one publisher per j)
    if (lane == 0)
        __hip_atomic_store(&rring[j], pack_th(1u, h0[(L2 ? HDIM : 0) + j]),
                           __ATOMIC_RELAXED, __HIP_MEMORY_SCOPE_AGENT);

    // ---- feed(0) into registers -------------------------------------------
    float fv[8];
    if (!L2) {
#pragma unroll
        for (int u = 0; u < 8; ++u) fv[u] = x[lane + 64 * u];
    } else {
        // h1(0-output) = ring0 slot 1, tag 2
        {   // sentinel pre-spin
            const ull* sent = ring0 + (size_t)1 * HDIM + SENT;
            while ((unsigned)(__hip_atomic_load(sent, __ATOMIC_RELAXED,
                                                __HIP_MEMORY_SCOPE_AGENT) >> 32) != 2u)
                __builtin_amdgcn_s_sleep(1);
        }
        const ull* s = ring0 + (size_t)1 * HDIM + lane;
        ull p[8];
#pragma unroll
        for (int u = 0; u < 8; ++u)
            p[u] = __hip_atomic_load(&s[64 * u], __ATOMIC_RELAXED, __HIP_MEMORY_SCOPE_AGENT);
        bool ok;
        do {
            ok = true;
#pragma unroll
            for (int u = 0; u < 8; ++u)
                if ((unsigned)(p[u] >> 32) != 2u) {
                    p[u] = __hip_atomic_load(&s[64 * u], __ATOMIC_RELAXED, __HIP_MEMORY_SCOPE_AGENT);
                    ok &= ((unsigned)(p[u] >> 32) == 2u);
                }
        } while (!ok);
#pragma unroll
        for (int u = 0; u < 8; ++u) fv[u] = unpack_v(p[u]);
    }

    for (int t = 0; t < TSTEPS; ++t) {
        // ---- recurrent poll straight into registers (critical path) -------
        float hv[8];
        {
            const unsigned tg = (unsigned)(t + 1);
            {   // sentinel pre-spin: 8B/wave/round instead of 4KB
                const ull* sent = rring + (size_t)t * HDIM + SENT;
                while ((unsigned)(__hip_atomic_load(sent, __ATOMIC_RELAXED,
                                                    __HIP_MEMORY_SCOPE_AGENT) >> 32) != tg)
                    __builtin_amdgcn_s_sleep(1);
            }
            const ull* s = rring + (size_t)t * HDIM + lane;
            ull p[8];
#pragma unroll
            for (int u = 0; u < 8; ++u)
                p[u] = __hip_atomic_load(&s[64 * u], __ATOMIC_RELAXED, __HIP_MEMORY_SCOPE_AGENT);
            bool ok;                      // fixup: slots are self-validating
            do {
                ok = true;
#pragma unroll
                for (int u = 0; u < 8; ++u)
                    if ((unsigned)(p[u] >> 32) != tg) {
                        p[u] = __hip_atomic_load(&s[64 * u], __ATOMIC_RELAXED, __HIP_MEMORY_SCOPE_AGENT);
                        ok &= ((unsigned)(p[u] >> 32) == tg);
                    }
            } while (!ok);
#pragma unroll
            for (int u = 0; u < 8; ++u) hv[u] = unpack_v(p[u]);
        }

        // ---- 4-row partial dot (recurrent + feed) -------------------------
        float a0 = 0.f, a1 = 0.f, a2 = 0.f, a3 = 0.f;
#pragma unroll
        for (int u = 0; u < 8; ++u) {
            a0 += wA[0][u] * hv[u]; a1 += wA[1][u] * hv[u];
            a2 += wA[2][u] * hv[u]; a3 += wA[3][u] * hv[u];
        }
#pragma unroll
        for (int u = 0; u < 8; ++u) {
            a0 += wB[0][u] * fv[u]; a1 += wB[1][u] * fv[u];
            a2 += wB[2][u] * fv[u]; a3 += wB[3][u] * fv[u];
        }

        // ---- wave butterfly: every lane gets all 4 gate sums --------------
#pragma unroll
        for (int m = 1; m < 64; m <<= 1) {
            a0 += __shfl_xor(a0, m);
            a1 += __shfl_xor(a1, m);
            a2 += __shfl_xor(a2, m);
            a3 += __shfl_xor(a3, m);
        }

        const float iv = 1.f / (1.f + __expf(-(a0 + bb[0])));
        const float ff = 1.f / (1.f + __expf(-(a1 + bb[1])));
        const float gg = 1.f - 2.f / (__expf(2.f * (a2 + bb[2])) + 1.f);
        const float ov = 1.f / (1.f + __expf(-(a3 + bb[3])));
        c = ff * c + iv * gg;
        const float h = ov * (1.f - 2.f / (__expf(2.f * c) + 1.f));

        // ---- publish (lane 0); h2seq store off-path (lane 1) --------------
        if (lane == 0)
            __hip_atomic_store(&rring[(size_t)(t + 1) * HDIM + j],
                               pack_th((unsigned)(t + 2), h),
                               __ATOMIC_RELAXED, __HIP_MEMORY_SCOPE_AGENT);
        if (L2 && lane == 1)
            h2seq[(size_t)t * HDIM + j] = h;

        // ---- feed(t+1) (off critical path; L1 runs ahead of L2) -----------
        if (t + 1 < TSTEPS) {
            if (!L2) {
#pragma unroll
                for (int u = 0; u < 8; ++u)
                    fv[u] = x[(size_t)(t + 1) * HDIM + lane + 64 * u];
            } else {
                const unsigned tg = (unsigned)(t + 3);     // h1 seq t+2
                {
                    const ull* sent = ring0 + (size_t)(t + 2) * HDIM + SENT;
                    while ((unsigned)(__hip_atomic_load(sent, __ATOMIC_RELAXED,
                                                        __HIP_MEMORY_SCOPE_AGENT) >> 32) != tg)
                        __builtin_amdgcn_s_sleep(2);
                }
                const ull* s = ring0 + (size_t)(t + 2) * HDIM + lane;
                ull p[8];
#pragma unroll
                for (int u = 0; u < 8; ++u)
                    p[u] = __hip_atomic_load(&s[64 * u], __ATOMIC_RELAXED, __HIP_MEMORY_SCOPE_AGENT);
                bool ok;
                do {
                    ok = true;
#pragma unroll
                    for (int u = 0; u < 8; ++u)
                        if ((unsigned)(p[u] >> 32) != tg) {
                            p[u] = __hip_atomic_load(&s[64 * u], __ATOMIC_RELAXED, __HIP_MEMORY_SCOPE_AGENT);
                            ok &= ((unsigned)(p[u] >> 32) == tg);
                        }
                } while (!ok);
#pragma unroll
                for (int u = 0; u < 8; ++u) fv[u] = unpack_v(p[u]);
            }
        }
    }
}

// ---------------------------------------------------------------------------
// Head + BCE loss.
// ---------------------------------------------------------------------------
__global__ __launch_bounds__(256) void head_loss(
    const float* __restrict__ h2,   // [T][512]
    const float* __restrict__ Wh,   // [2][512]
    const float* __restrict__ bh,   // [2]
    const float* __restrict__ y,    // [T][2]
    float* __restrict__ out)
{
    const int tid  = threadIdx.x;
    const int lane = tid & 63;
    const int wv   = tid >> 6;
    const int gw   = blockIdx.x * 4 + wv;   // 0..1023

    float w0[8], w1[8];
#pragma unroll
    for (int u = 0; u < 8; ++u) {
        w0[u] = Wh[lane * 8 + u];
        w1[u] = Wh[HDIM + lane * 8 + u];
    }

    float lsum = 0.f;
    for (int t = gw; t < TSTEPS; t += 1024) {
        const float* hp = h2 + (size_t)t * HDIM + lane * 8;
        float4 hv0 = *(const float4*)&hp[0];
        float4 hv1 = *(const float4*)&hp[4];
        float a0 = hv0.x * w0[0] + hv0.y * w0[1] + hv0.z * w0[2] + hv0.w * w0[3]
                 + hv1.x * w0[4] + hv1.y * w0[5] + hv1.z * w0[6] + hv1.w * w0[7];
        float a1 = hv0.x * w1[0] + hv0.y * w1[1] + hv0.z * w1[2] + hv0.w * w1[3]
                 + hv1.x * w1[4] + hv1.y * w1[5] + hv1.z * w1[6] + hv1.w * w1[7];
#pragma unroll
        for (int m = 1; m < 64; m <<= 1) {
            a0 += __shfl_xor(a0, m);
            a1 += __shfl_xor(a1, m);
        }
        if (lane == 0) {
            const float z0 = a0 + bh[0];
            const float z1 = a1 + bh[1];
            const float p0 = 1.f / (1.f + __expf(-z0));
            const float p1 = 1.f / (1.f + __expf(-z1));
            const float lp0  = fmaxf(__logf(p0), -100.f);
            const float lp1  = fmaxf(__logf(p1), -100.f);
            const float l1p0 = fmaxf(log1pf(-p0), -100.f);
            const float l1p1 = fmaxf(log1pf(-p1), -100.f);
            const float y0 = y[(size_t)t * 2 + 0];
            const float y1 = y[(size_t)t * 2 + 1];
            lsum += y0 * lp0 + (1.f - y0) * l1p0;
            lsum += y1 * lp1 + (1.f - y1) * l1p1;
        }
    }

    __shared__ float red[4];
    if (lane == 0) red[wv] = lsum;
    __syncthreads();
    if (tid == 0) {
        const float ssum = red[0] + red[1] + red[2] + red[3];
        atomicAdd(out, ssum * (-1.f / (float)(TSTEPS * 2)));
    }
}

// ---------------------------------------------------------------------------
extern "C" void kernel_launch(void* const* d_in, const int* in_sizes, int n_in,
                              void* d_out, int out_size, void* d_ws, size_t ws_size,
                              hipStream_t stream)
{
    const float* x     = (const float*)d_in[0];   // [8192][1][512]
    const float* truth = (const float*)d_in[1];   // [8192][1][2]
    const float* h0    = (const float*)d_in[2];   // [2][1][512]
    const float* c0    = (const float*)d_in[3];   // [2][1][512]
    const float* Wih0  = (const float*)d_in[4];
    const float* Whh0  = (const float*)d_in[5];
    const float* bih0  = (const float*)d_in[6];
    const float* bhh0  = (const float*)d_in[7];
    const float* Wih1  = (const float*)d_in[8];
    const float* Whh1  = (const float*)d_in[9];
    const float* bih1  = (const float*)d_in[10];
    const float* bhh1  = (const float*)d_in[11];
    const float* Whead = (const float*)d_in[12];
    const float* bhead = (const float*)d_in[13];

    char* ws = (char*)d_ws;
    ull*   ring0 = (ull*)ws;                               // 33.6 MB [8194][512]
    ull*   ring1 = (ull*)(ws + (((size_t)34) << 20));      // 33.6 MB [8194][512]
    float* h2seq = (float*)(ws + (((size_t)68) << 20));    // 16 MB  [T][512]

    hipMemsetAsync(d_out, 0, (size_t)out_size * sizeof(float), stream);

    lstm_fused<<<256, 256, 0, stream>>>(x, Whh0, Wih0, bih0, bhh0,
                                        Wih1, Whh1, bih1, bhh1,
                                        h0, c0, h2seq, ring0, ring1);
    head_loss<<<256, 256, 0, stream>>>(h2seq, Whead, bhead, truth, (float*)d_out);
}

// Round 7
// 14759.117 us; speedup vs baseline: 2.0810x; 2.0810x over previous
//
#include <hip/hip_runtime.h>
#include <stdint.h>

#define TSTEPS 8192
#define HDIM 512
#define LDS_BYTES 139264   // 32*512*2 weights + 2*512*2 h-buffers, f32

typedef unsigned long long ull;

// ---------------------------------------------------------------------------
__device__ __forceinline__ ull pack_th(unsigned tag, float v) {
    union { float f; unsigned u; } x; x.f = v;
    return ((ull)tag << 32) | (ull)x.u;
}
__device__ __forceinline__ float unpack_v(ull p) {
    union { unsigned u; float f; } x; x.u = (unsigned)p;
    return x.f;
}

// ---------------------------------------------------------------------------
// Fused 2-layer persistent LSTM. 128 WGs x 256 threads, 1 WG/CU (136KB LDS).
//   blocks 0..63  : layer 1.  recurrent = Whh0 @ h1(t-1), feed = Wih0 @ x(t)
//   blocks 64..127: layer 2.  recurrent = Whh1 @ h2(t-1), feed = Wih1 @ h1(t)
// WG w owns hidden units j in [w*8, w*8+8).
//
// WEIGHTS LIVE IN LDS (the fix for R3/R5's register-allocator defeats):
//   sWA[32][512] = recurrent rows (row_local = g*8+ju), sWB = feed rows.
//   Loaded once at kernel start; regalloc can't spill them. Reads use the
//   quad-rotation ((u+kk)&15) so each b128 instruction tiles all 32 banks
//   at the 1KB/instr floor; h reads are 8-lane broadcasts (conflict-free).
//
// Thread layout (R2-proven): lane = jj*32 + g*8 + kk; thread's dot chunk is
// k in [kk*64, kk*64+64). 3-level shfl_xor reduce over kk, shfl-gather the
// 4 gates, redundant c/h update per lane group.
//
// Rings are FULL-HISTORY {tag,value} 8B slots (slot s = state after s steps,
// tag s+1; written once; no back-pressure; L1 never waits for L2).
// Tags <= 8194: poison 0xAAAAAAAA / 0x00000000 never match.
// Per-thread 2-slot poll -> LDS hA double-buffer -> ONE barrier per step
// (barrier(t+1) separates iter-t readers from iter-t+2 writers).
// Feed staged one step ahead (x prefetched; h1 polled after publish, off the
// critical path since L1 runs ahead of L2 by a constant skew).
// ---------------------------------------------------------------------------
__global__ __launch_bounds__(256, 1) void lstm_fused(
    const float* __restrict__ x,      // [T][512]
    const float* __restrict__ Whh0,   // [2048][512]
    const float* __restrict__ Wih0,   // [2048][512]
    const float* __restrict__ bih0,   // [2048]
    const float* __restrict__ bhh0,   // [2048]
    const float* __restrict__ Wih1,   // [2048][512]
    const float* __restrict__ Whh1,   // [2048][512]
    const float* __restrict__ bih1,   // [2048]
    const float* __restrict__ bhh1,   // [2048]
    const float* __restrict__ h0,     // [2][512]
    const float* __restrict__ c0,     // [2][512]
    float* __restrict__ h2seq,        // [T][512]
    ull* __restrict__ ring0,          // [T+2][512]
    ull* __restrict__ ring1)          // [T+2][512]
{
    extern __shared__ float lds[];
    float* sWA = lds;            // [32][512] recurrent weights
    float* sWB = lds + 16384;    // [32][512] feed weights
    float* hAb = lds + 32768;    // [2][512]  recurrent h, double-buffered
    float* hBb = lds + 33792;    // [2][512]  feed vector, double-buffered

    const int L2   = (blockIdx.x >= 64) ? 1 : 0;
    const int w    = L2 ? (int)blockIdx.x - 64 : (int)blockIdx.x;
    const int tid  = threadIdx.x;
    const int wave = tid >> 6;
    const int lane = tid & 63;
    const int jj   = lane >> 5;
    const int g    = (lane >> 3) & 3;
    const int kk   = lane & 7;
    const int ju   = wave * 2 + jj;       // 0..7 unit within WG
    const int j    = w * 8 + ju;          // global hidden unit
    const int row_local = g * 8 + ju;     // 0..31 LDS weight row
    const int grow = g * HDIM + j;        // global weight row

    ull* rring = L2 ? ring1 : ring0;      // recurrent (self) ring

    // ---- initial state publish FIRST (maximum propagation slack) ----------
    if (lane == jj * 32)
        __hip_atomic_store(&rring[j], pack_th(1u, h0[(L2 ? HDIM : 0) + j]),
                           __ATOMIC_RELAXED, __HIP_MEMORY_SCOPE_AGENT);

    // ---- stage weights into LDS (once) ------------------------------------
    {
        const float* WA = L2 ? Whh1 : Whh0;
        const float* WB = L2 ? Wih1 : Wih0;
        const int r   = tid >> 3;         // 0..31 row_local
        const int sub = tid & 7;          // 0..7  64-float chunk
        const int rg  = r >> 3;
        const int rju = r & 7;
        const size_t gr = (size_t)(rg * HDIM + w * 8 + rju) * HDIM + sub * 64;
        float4* dA = (float4*)&sWA[r * 512 + sub * 64];
        float4* dB = (float4*)&sWB[r * 512 + sub * 64];
        const float4* sA = (const float4*)&WA[gr];
        const float4* sB = (const float4*)&WB[gr];
#pragma unroll
        for (int q = 0; q < 16; ++q) { dA[q] = sA[q]; dB[q] = sB[q]; }
    }

    // ---- feed(0) -> hBb[0] -------------------------------------------------
    if (!L2) {
        float2 v = *(const float2*)&x[2 * tid];
        hBb[2 * tid] = v.x; hBb[2 * tid + 1] = v.y;
    } else {
        const ull* s = ring0 + (size_t)1 * HDIM;   // h1(0) = slot 1, tag 2
        ull p0 = __hip_atomic_load(&s[2 * tid],     __ATOMIC_RELAXED, __HIP_MEMORY_SCOPE_AGENT);
        ull p1 = __hip_atomic_load(&s[2 * tid + 1], __ATOMIC_RELAXED, __HIP_MEMORY_SCOPE_AGENT);
        while ((unsigned)(p0 >> 32) != 2u || (unsigned)(p1 >> 32) != 2u) {
            __builtin_amdgcn_s_sleep(1);
            p0 = __hip_atomic_load(&s[2 * tid],     __ATOMIC_RELAXED, __HIP_MEMORY_SCOPE_AGENT);
            p1 = __hip_atomic_load(&s[2 * tid + 1], __ATOMIC_RELAXED, __HIP_MEMORY_SCOPE_AGENT);
        }
        hBb[2 * tid]     = unpack_v(p0);
        hBb[2 * tid + 1] = unpack_v(p1);
    }

    const float bias = L2 ? (bih1[grow] + bhh1[grow]) : (bih0[grow] + bhh0[grow]);
    float c = c0[(L2 ? HDIM : 0) + j];

    __syncthreads();   // weights + hBb[0] ready

    for (int t = 0; t < TSTEPS; ++t) {
        const int p = t & 1;

        // ---- L1: prefetch x(t+1) (independent of recurrence) --------------
        float2 xn;
        if (!L2 && t + 1 < TSTEPS)
            xn = *(const float2*)&x[(size_t)(t + 1) * HDIM + 2 * tid];

        // ---- poll recurrent ring row t (tag t+1) -> hAb[p] ----------------
        {
            const ull* s = rring + (size_t)t * HDIM;
            const unsigned tg = (unsigned)(t + 1);
            ull p0 = __hip_atomic_load(&s[2 * tid],     __ATOMIC_RELAXED, __HIP_MEMORY_SCOPE_AGENT);
            ull p1 = __hip_atomic_load(&s[2 * tid + 1], __ATOMIC_RELAXED, __HIP_MEMORY_SCOPE_AGENT);
            while ((unsigned)(p0 >> 32) != tg || (unsigned)(p1 >> 32) != tg) {
                __builtin_amdgcn_s_sleep(1);
                p0 = __hip_atomic_load(&s[2 * tid],     __ATOMIC_RELAXED, __HIP_MEMORY_SCOPE_AGENT);
                p1 = __hip_atomic_load(&s[2 * tid + 1], __ATOMIC_RELAXED, __HIP_MEMORY_SCOPE_AGENT);
            }
            hAb[p * 512 + 2 * tid]     = unpack_v(p0);
            hAb[p * 512 + 2 * tid + 1] = unpack_v(p1);
        }
        __syncthreads();   // the ONE barrier per step

        // ---- dots from LDS (quad-rotated: bank-tiling at the b128 floor) --
        const float* wa = &sWA[row_local * 512 + kk * 64];
        const float* wb = &sWB[row_local * 512 + kk * 64];
        const float* ha = &hAb[p * 512 + kk * 64];
        const float* hb = &hBb[p * 512 + kk * 64];
        float s0 = 0.f, s1 = 0.f, s2 = 0.f, s3 = 0.f;
#pragma unroll
        for (int u = 0; u < 16; ++u) {
            const int q = ((u + kk) & 15) * 4;
            const float4 wq = *(const float4*)&wa[q];
            const float4 hq = *(const float4*)&ha[q];
            s0 += wq.x * hq.x; s1 += wq.y * hq.y;
            s2 += wq.z * hq.z; s3 += wq.w * hq.w;
        }
#pragma unroll
        for (int u = 0; u < 16; ++u) {
            const int q = ((u + kk) & 15) * 4;
            const float4 wq = *(const float4*)&wb[q];
            const float4 hq = *(const float4*)&hb[q];
            s0 += wq.x * hq.x; s1 += wq.y * hq.y;
            s2 += wq.z * hq.z; s3 += wq.w * hq.w;
        }
        float s = (s0 + s1) + (s2 + s3);

        // reduce across the 8 kk lanes
        s += __shfl_xor(s, 1);
        s += __shfl_xor(s, 2);
        s += __shfl_xor(s, 4);
        s += bias;

        // branchless: gates sigma(s); cell-gate tanh(s) = 2*sigma(2s)-1
        const float sc  = (g == 2) ? 2.f : 1.f;
        const float sig = 1.f / (1.f + __expf(-sc * s));
        const float act = sc * sig - (sc - 1.f);

        const int base = jj * 32 + kk;
        const float iv = __shfl(act, base);
        const float fv = __shfl(act, base + 8);
        const float gv = __shfl(act, base + 16);
        const float ov = __shfl(act, base + 24);

        c = fv * c + iv * gv;
        const float h = ov * (1.f - 2.f / (__expf(2.f * c) + 1.f));

        // ---- publish (lane 0 of each unit); h2seq store on lane 1 ---------
        if (lane == jj * 32)
            __hip_atomic_store(&rring[(size_t)(t + 1) * HDIM + j],
                               pack_th((unsigned)(t + 2), h),
                               __ATOMIC_RELAXED, __HIP_MEMORY_SCOPE_AGENT);
        if (L2 && lane == jj * 32 + 1)
            h2seq[(size_t)t * HDIM + j] = h;

        // ---- stage feed(t+1) -> hBb[1-p] (off critical path) --------------
        if (t + 1 < TSTEPS) {
            if (!L2) {
                hBb[(1 - p) * 512 + 2 * tid]     = xn.x;
                hBb[(1 - p) * 512 + 2 * tid + 1] = xn.y;
            } else {
                const ull* s2 = ring0 + (size_t)(t + 2) * HDIM;  // h1(t+1)
                const unsigned tg = (unsigned)(t + 3);
                ull q0 = __hip_atomic_load(&s2[2 * tid],     __ATOMIC_RELAXED, __HIP_MEMORY_SCOPE_AGENT);
                ull q1 = __hip_atomic_load(&s2[2 * tid + 1], __ATOMIC_RELAXED, __HIP_MEMORY_SCOPE_AGENT);
                while ((unsigned)(q0 >> 32) != tg || (unsigned)(q1 >> 32) != tg) {
                    __builtin_amdgcn_s_sleep(1);
                    q0 = __hip_atomic_load(&s2[2 * tid],     __ATOMIC_RELAXED, __HIP_MEMORY_SCOPE_AGENT);
                    q1 = __hip_atomic_load(&s2[2 * tid + 1], __ATOMIC_RELAXED, __HIP_MEMORY_SCOPE_AGENT);
                }
                hBb[(1 - p) * 512 + 2 * tid]     = unpack_v(q0);
                hBb[(1 - p) * 512 + 2 * tid + 1] = unpack_v(q1);
            }
        }
    }
}

// ---------------------------------------------------------------------------
// Head + BCE loss.
// ---------------------------------------------------------------------------
__global__ __launch_bounds__(256) void head_loss(
    const float* __restrict__ h2,   // [T][512]
    const float* __restrict__ Wh,   // [2][512]
    const float* __restrict__ bh,   // [2]
    const float* __restrict__ y,    // [T][2]
    float* __restrict__ out)
{
    const int tid  = threadIdx.x;
    const int lane = tid & 63;
    const int wv   = tid >> 6;
    const int gw   = blockIdx.x * 4 + wv;   // 0..1023

    float w0[8], w1[8];
#pragma unroll
    for (int u = 0; u < 8; ++u) {
        w0[u] = Wh[lane * 8 + u];
        w1[u] = Wh[HDIM + lane * 8 + u];
    }

    float lsum = 0.f;
    for (int t = gw; t < TSTEPS; t += 1024) {
        const float* hp = h2 + (size_t)t * HDIM + lane * 8;
        float4 hv0 = *(const float4*)&hp[0];
        float4 hv1 = *(const float4*)&hp[4];
        float a0 = hv0.x * w0[0] + hv0.y * w0[1] + hv0.z * w0[2] + hv0.w * w0[3]
                 + hv1.x * w0[4] + hv1.y * w0[5] + hv1.z * w0[6] + hv1.w * w0[7];
        float a1 = hv0.x * w1[0] + hv0.y * w1[1] + hv0.z * w1[2] + hv0.w * w1[3]
                 + hv1.x * w1[4] + hv1.y * w1[5] + hv1.z * w1[6] + hv1.w * w1[7];
#pragma unroll
        for (int m = 1; m < 64; m <<= 1) {
            a0 += __shfl_xor(a0, m);
            a1 += __shfl_xor(a1, m);
        }
        if (lane == 0) {
            const float z0 = a0 + bh[0];
            const float z1 = a1 + bh[1];
            const float p0 = 1.f / (1.f + __expf(-z0));
            const float p1 = 1.f / (1.f + __expf(-z1));
            const float lp0  = fmaxf(__logf(p0), -100.f);
            const float lp1  = fmaxf(__logf(p1), -100.f);
            const float l1p0 = fmaxf(log1pf(-p0), -100.f);
            const float l1p1 = fmaxf(log1pf(-p1), -100.f);
            const float y0 = y[(size_t)t * 2 + 0];
            const float y1 = y[(size_t)t * 2 + 1];
            lsum += y0 * lp0 + (1.f - y0) * l1p0;
            lsum += y1 * lp1 + (1.f - y1) * l1p1;
        }
    }

    __shared__ float red[4];
    if (lane == 0) red[wv] = lsum;
    __syncthreads();
    if (tid == 0) {
        const float ssum = red[0] + red[1] + red[2] + red[3];
        atomicAdd(out, ssum * (-1.f / (float)(TSTEPS * 2)));
    }
}

// ---------------------------------------------------------------------------
extern "C" void kernel_launch(void* const* d_in, const int* in_sizes, int n_in,
                              void* d_out, int out_size, void* d_ws, size_t ws_size,
                              hipStream_t stream)
{
    const float* x     = (const float*)d_in[0];   // [8192][1][512]
    const float* truth = (const float*)d_in[1];   // [8192][1][2]
    const float* h0    = (const float*)d_in[2];   // [2][1][512]
    const float* c0    = (const float*)d_in[3];   // [2][1][512]
    const float* Wih0  = (const float*)d_in[4];
    const float* Whh0  = (const float*)d_in[5];
    const float* bih0  = (const float*)d_in[6];
    const float* bhh0  = (const float*)d_in[7];
    const float* Wih1  = (const float*)d_in[8];
    const float* Whh1  = (const float*)d_in[9];
    const float* bih1  = (const float*)d_in[10];
    const float* bhh1  = (const float*)d_in[11];
    const float* Whead = (const float*)d_in[12];
    const float* bhead = (const float*)d_in[13];

    char* ws = (char*)d_ws;
    ull*   ring0 = (ull*)ws;                               // 33.6 MB [8194][512]
    ull*   ring1 = (ull*)(ws + (((size_t)34) << 20));      // 33.6 MB [8194][512]
    float* h2seq = (float*)(ws + (((size_t)68) << 20));    // 16 MB  [T][512]

    hipMemsetAsync(d_out, 0, (size_t)out_size * sizeof(float), stream);

    // allow >64KB dynamic LDS (gfx950 supports up to 160KB/WG)
    hipFuncSetAttribute((const void*)lstm_fused,
                        hipFuncAttributeMaxDynamicSharedMemorySize, LDS_BYTES);

    lstm_fused<<<128, 256, LDS_BYTES, stream>>>(x, Whh0, Wih0, bih0, bhh0,
                                                Wih1, Whh1, bih1, bhh1,
                                                h0, c0, h2seq, ring0, ring1);
    head_loss<<<256, 256, 0, stream>>>(h2seq, Whead, bhead, truth, (float*)d_out);
}